// Round 5
// baseline (142.848 us; speedup 1.0000x reference)
//
#include <hip/hip_runtime.h>

#define NN 100000
#define NE 1600000
#define NH 64
#define NG 64

#define RSH 9
#define RNG 512            // bucket width (nodes per bucket)
#define RB  196            // ceil(NN/RNG)
#define BB  256            // count/scatter blocks

static constexpr int TPB = 256;

// ================= bucket build =================

// counts per (block, bucket); block 0 also zeros the small accumulators
__global__ __launch_bounds__(1024) void k_count(const int* __restrict__ dst,
                                                int* __restrict__ cntmat,
                                                float* __restrict__ scal,
                                                float* __restrict__ pooled,
                                                float* __restrict__ cnt) {
    __shared__ int cl[RB];
    for (int i = threadIdx.x; i < RB; i += 1024) cl[i] = 0;
    __syncthreads();
    int b = blockIdx.x;
    long e0 = ((long)b * NE / BB) & ~3L;
    long e1 = (b == BB - 1) ? NE : (((long)(b + 1) * NE / BB) & ~3L);
    for (long e = e0 + (long)threadIdx.x * 4; e < e1; e += 4096L) {
        int4 d4 = *reinterpret_cast<const int4*>(dst + e);
        atomicAdd(&cl[d4.x >> RSH], 1);
        atomicAdd(&cl[d4.y >> RSH], 1);
        atomicAdd(&cl[d4.z >> RSH], 1);
        atomicAdd(&cl[d4.w >> RSH], 1);
    }
    __syncthreads();
    for (int i = threadIdx.x; i < RB; i += 1024) cntmat[b * RB + i] = cl[i];
    if (b == 0) {
        if (threadIdx.x < 2)   scal[threadIdx.x] = 0.f;
        if (threadIdx.x < 128) pooled[threadIdx.x] = 0.f;
        if (threadIdx.x < NG)  cnt[threadIdx.x] = 0.f;
    }
}

// scan: relative per-(block,bucket) offsets + bucket bases. 1 block, 16 waves.
__global__ __launch_bounds__(1024) void k_scan(const int* __restrict__ cntmat,
                                               int* __restrict__ startmat,
                                               int* __restrict__ bmeta) {
    __shared__ int colsum[RB];
    int w = threadIdx.x >> 6, lane = threadIdx.x & 63;
    for (int r = w; r < RB; r += 16) {
        int carry = 0;
        for (int i = 0; i < BB / 64; ++i) {
            int b = i * 64 + lane;
            int v = cntmat[b * RB + r];
            int inc = v;
            for (int off = 1; off < 64; off <<= 1) {
                int t = __shfl_up(inc, off);
                if (lane >= off) inc += t;
            }
            startmat[b * RB + r] = carry + (inc - v);
            carry += __shfl(inc, 63);
        }
        colsum[r] = carry;
    }
    __syncthreads();
    if (threadIdx.x == 0) {
        int acc = 0;
        for (int r = 0; r < RB; ++r) { bmeta[r] = acc; acc += colsum[r]; }
        bmeta[RB] = acc;
    }
}

// scatter edges into buckets: ebuf[slot] = { (dstoff<<17)|src , w }
__global__ __launch_bounds__(1024) void k_scatter(const int* __restrict__ src,
                                                  const int* __restrict__ dst,
                                                  const float* __restrict__ w,
                                                  const int* __restrict__ startmat,
                                                  const int* __restrict__ bmeta,
                                                  uint2* __restrict__ ebuf) {
    __shared__ int curs[RB];
    int b = blockIdx.x;
    for (int i = threadIdx.x; i < RB; i += 1024) curs[i] = startmat[b * RB + i] + bmeta[i];
    __syncthreads();
    long e0 = ((long)b * NE / BB) & ~3L;
    long e1 = (b == BB - 1) ? NE : (((long)(b + 1) * NE / BB) & ~3L);
    for (long e = e0 + (long)threadIdx.x * 4; e < e1; e += 4096L) {
        int4 d4 = *reinterpret_cast<const int4*>(dst + e);
        int4 s4 = *reinterpret_cast<const int4*>(src + e);
        float4 w4 = *reinterpret_cast<const float4*>(w + e);
        int dd[4] = {d4.x, d4.y, d4.z, d4.w};
        int ss[4] = {s4.x, s4.y, s4.z, s4.w};
        float wv[4] = {w4.x, w4.y, w4.z, w4.w};
#pragma unroll
        for (int k = 0; k < 4; ++k) {
            int r = dd[k] >> RSH;
            int slot = atomicAdd(&curs[r], 1);
            unsigned pack = ((unsigned)(dd[k] & (RNG - 1)) << 17) | (unsigned)ss[k];
            ebuf[slot] = make_uint2(pack, __float_as_uint(wv[k]));
        }
    }
}

// ================= fused gather passes (one block per bucket) =================

// deg: bins += w; then dinv/g1 finalized for this block's node range + graph counts
__global__ __launch_bounds__(1024) void kB_deg(const uint2* __restrict__ ebuf,
                                               const int* __restrict__ bmeta,
                                               const float* __restrict__ x,
                                               const int* __restrict__ batch,
                                               float* __restrict__ dinv,
                                               float* __restrict__ g1,
                                               float* __restrict__ cnt) {
    __shared__ float bins[RNG];
    __shared__ int hist[NG];
    int r = blockIdx.x;
    if (threadIdx.x < RNG) bins[threadIdx.x] = 0.f;
    if (threadIdx.x >= RNG && threadIdx.x < RNG + NG) hist[threadIdx.x - RNG] = 0;
    __syncthreads();
    int s = bmeta[r], e = bmeta[r + 1];
    for (int i = s + threadIdx.x; i < e; i += 1024) {
        uint2 ed = ebuf[i];
        atomicAdd(&bins[ed.x >> 17], __uint_as_float(ed.y));
    }
    __syncthreads();
    int base = r * RNG;
    int len = min(RNG, NN - base);
    if (threadIdx.x < len) {
        int n = base + threadIdx.x;
        float di = rsqrtf(bins[threadIdx.x] + 1.0f);
        dinv[n] = di;
        g1[n] = di * x[n];
        atomicAdd(&hist[batch[n]], 1);
    }
    __syncthreads();
    if (threadIdx.x < NG && hist[threadIdx.x] > 0)
        atomicAdd(&cnt[threadIdx.x], (float)hist[threadIdx.x]);
}

// t1: bins += w*g1[src]; agg1 finalized for this range; BN sum/sumsq atomics
__global__ __launch_bounds__(1024) void kB_t1(const uint2* __restrict__ ebuf,
                                              const int* __restrict__ bmeta,
                                              const float* __restrict__ g1,
                                              const float* __restrict__ dinv,
                                              float* __restrict__ agg1,
                                              float* __restrict__ scal) {
    __shared__ float bins[RNG];
    int r = blockIdx.x;
    if (threadIdx.x < RNG) bins[threadIdx.x] = 0.f;
    __syncthreads();
    int s = bmeta[r], e = bmeta[r + 1];
    for (int i = s + threadIdx.x; i < e; i += 1024) {
        uint2 ed = ebuf[i];
        atomicAdd(&bins[ed.x >> 17], __uint_as_float(ed.y) * g1[ed.x & 0x1FFFF]);
    }
    __syncthreads();
    int base = r * RNG;
    int len = min(RNG, NN - base);
    float a = 0.f;
    if (threadIdx.x < len) {
        int n = base + threadIdx.x;
        a = dinv[n] * (bins[threadIdx.x] + g1[n]);
        agg1[n] = a;
    }
    // block reduce sum/sumsq
    float sm = a, q = a * a;
    for (int off = 32; off > 0; off >>= 1) {
        sm += __shfl_down(sm, off);
        q  += __shfl_down(q, off);
    }
    __shared__ float red[2][16];
    int wave = threadIdx.x >> 6, lane = threadIdx.x & 63;
    if (lane == 0) { red[0][wave] = sm; red[1][wave] = q; }
    __syncthreads();
    if (threadIdx.x == 0) {
        float ss = 0.f, qq = 0.f;
        for (int i = 0; i < 16; ++i) { ss += red[0][i]; qq += red[1][i]; }
        atomicAdd(&scal[0], ss);
        atomicAdd(&scal[1], qq);
    }
}

// node pass (prep inlined): g2[n][k] = dinv * sum_j relu((agg1-mu)*c[j]+beta[j]) * W2[j][k]
__global__ void k_node_hp(const float* __restrict__ agg1, const float* __restrict__ dinv,
                          const float* __restrict__ scal, const float* __restrict__ W1,
                          const float* __restrict__ gamma, const float* __restrict__ beta,
                          const float* __restrict__ W2, float* __restrict__ g2) {
    __shared__ float sc[NH], sb[NH], s0[NH], s1[NH];
    float mu  = scal[0] * (1.0f / NN);
    if (threadIdx.x < NH) {
        int j = threadIdx.x;
        float var = scal[1] * (1.0f / NN) - mu * mu;
        float w1 = W1[j];
        sc[j] = w1 * gamma[j] * rsqrtf(var * w1 * w1 + 1e-5f);
        sb[j] = beta[j]; s0[j] = W2[2 * j]; s1[j] = W2[2 * j + 1];
    }
    __syncthreads();
    int n = blockIdx.x * blockDim.x + threadIdx.x;
    if (n < NN) {
        float a = agg1[n] - mu;
        float h0 = 0.f, h1 = 0.f;
#pragma unroll
        for (int j = 0; j < NH; ++j) {
            float t = fmaxf(fmaf(a, sc[j], sb[j]), 0.f);
            h0 = fmaf(t, s0[j], h0);
            h1 = fmaf(t, s1[j], h1);
        }
        float di = dinv[n];
        g2[2 * n] = di * h0; g2[2 * n + 1] = di * h1;
    }
}

// t2: bins += w*g2[src]; agg2 finalized in-register; pooled via LDS graph bins
__global__ __launch_bounds__(1024) void kB_t2(const uint2* __restrict__ ebuf,
                                              const int* __restrict__ bmeta,
                                              const float* __restrict__ g2,
                                              const float* __restrict__ dinv,
                                              const int* __restrict__ batch,
                                              float* __restrict__ pooled) {
    __shared__ float2 bins[RNG];
    __shared__ float pl[NG][2];
    int r = blockIdx.x;
    if (threadIdx.x < RNG) bins[threadIdx.x] = make_float2(0.f, 0.f);
    if (threadIdx.x >= RNG && threadIdx.x < RNG + 2 * NG)
        ((float*)pl)[threadIdx.x - RNG] = 0.f;
    __syncthreads();
    int s = bmeta[r], e = bmeta[r + 1];
    for (int i = s + threadIdx.x; i < e; i += 1024) {
        uint2 ed = ebuf[i];
        int sidx = ed.x & 0x1FFFF;
        float ww = __uint_as_float(ed.y);
        float2 g = *reinterpret_cast<const float2*>(g2 + 2 * sidx);
        int off = ed.x >> 17;
        atomicAdd(&bins[off].x, ww * g.x);
        atomicAdd(&bins[off].y, ww * g.y);
    }
    __syncthreads();
    int base = r * RNG;
    int len = min(RNG, NN - base);
    if (threadIdx.x < len) {
        int n = base + threadIdx.x;
        float di = dinv[n];
        float a0 = di * (bins[threadIdx.x].x + g2[2 * n]);
        float a1 = di * (bins[threadIdx.x].y + g2[2 * n + 1]);
        int g = batch[n];
        atomicAdd(&pl[g][0], a0);
        atomicAdd(&pl[g][1], a1);
    }
    __syncthreads();
    if (threadIdx.x < NG) {
        float p0 = pl[threadIdx.x][0], p1 = pl[threadIdx.x][1];
        if (p0 != 0.f || p1 != 0.f) {
            atomicAdd(&pooled[2 * threadIdx.x],     p0);
            atomicAdd(&pooled[2 * threadIdx.x + 1], p1);
        }
    }
}

__global__ void k_final(const float* __restrict__ pooled, const float* __restrict__ cnt,
                        const float* __restrict__ b2, float* __restrict__ out) {
    int i = threadIdx.x;
    if (i < 2 * NG) {
        int g = i >> 1, k = i & 1;
        float cg = cnt[g];
        out[i] = pooled[i] / fmaxf(cg, 1.0f) + (cg > 0.f ? b2[k] : 0.f);
    }
}

// ================= fallback (atomic) path, used only if scratch is tiny =================

__global__ void k_edge_deg_fb(const int* __restrict__ dst, const float* __restrict__ w,
                              float* __restrict__ deg) {
    int gid = blockIdx.x * blockDim.x + threadIdx.x;
    int T = gridDim.x * blockDim.x;
    for (int e = gid; e < NE; e += T) atomicAdd(&deg[dst[e]], w[e]);
}

__global__ void k_node_dinv_fb(const float* __restrict__ x, float* __restrict__ deg,
                               float* __restrict__ agg1, float* __restrict__ scal) {
    int gid = blockIdx.x * blockDim.x + threadIdx.x;
    int T = gridDim.x * blockDim.x;
    for (int n = gid; n < NN; n += T) {
        float di = rsqrtf(deg[n] + 1.0f);
        deg[n] = di;
        agg1[n] = di * di * x[n];
    }
    if (gid == 0) { scal[0] = 0.f; scal[1] = 0.f; }
}

__global__ void k_edge_agg1_fb(const int* __restrict__ src, const int* __restrict__ dst,
                               const float* __restrict__ w, const float* __restrict__ dinv,
                               const float* __restrict__ x, float* __restrict__ agg1) {
    int gid = blockIdx.x * blockDim.x + threadIdx.x;
    int T = gridDim.x * blockDim.x;
    for (int e = gid; e < NE; e += T) {
        int s = src[e], d = dst[e];
        atomicAdd(&agg1[d], dinv[s] * w[e] * dinv[d] * x[s]);
    }
}

__global__ void k_reduce_fb(const float* __restrict__ agg1, float* __restrict__ scal) {
    float s = 0.f, q = 0.f;
    int gid = blockIdx.x * blockDim.x + threadIdx.x;
    int T = gridDim.x * blockDim.x;
    for (int n = gid; n < NN; n += T) { float a = agg1[n]; s += a; q += a * a; }
    for (int off = 32; off > 0; off >>= 1) { s += __shfl_down(s, off); q += __shfl_down(q, off); }
    __shared__ float red[2][4];
    int wave = threadIdx.x >> 6, lane = threadIdx.x & 63;
    if (lane == 0) { red[0][wave] = s; red[1][wave] = q; }
    __syncthreads();
    if (threadIdx.x == 0) {
        atomicAdd(&scal[0], red[0][0] + red[0][1] + red[0][2] + red[0][3]);
        atomicAdd(&scal[1], red[1][0] + red[1][1] + red[1][2] + red[1][3]);
    }
}

__global__ void k_prep_fb(float* __restrict__ scal, const float* __restrict__ W1,
                          const float* __restrict__ gamma, float* __restrict__ c,
                          float* __restrict__ pooled, float* __restrict__ cnt) {
    int j = threadIdx.x;
    float mu  = scal[0] * (1.0f / NN);
    float var = scal[1] * (1.0f / NN) - mu * mu;
    float w1 = W1[j];
    c[j] = w1 * gamma[j] * rsqrtf(var * w1 * w1 + 1e-5f);
    pooled[2 * j] = 0.f; pooled[2 * j + 1] = 0.f; cnt[j] = 0.f;
    if (j == 0) scal[2] = mu;
}

__global__ void k_node_hp_fb(const float* __restrict__ agg1, const float* __restrict__ dinv,
                             const float* __restrict__ c, const float* __restrict__ beta,
                             const float* __restrict__ W2, const float* __restrict__ scal,
                             float* __restrict__ hp, float* __restrict__ agg2) {
    __shared__ float sc[NH], sb[NH], s0[NH], s1[NH];
    if (threadIdx.x < NH) {
        int j = threadIdx.x;
        sc[j] = c[j]; sb[j] = beta[j]; s0[j] = W2[2 * j]; s1[j] = W2[2 * j + 1];
    }
    __syncthreads();
    float mu = scal[2];
    int n = blockIdx.x * blockDim.x + threadIdx.x;
    if (n < NN) {
        float a = agg1[n] - mu;
        float h0 = 0.f, h1 = 0.f;
#pragma unroll
        for (int j = 0; j < NH; ++j) {
            float t = fmaxf(fmaf(a, sc[j], sb[j]), 0.f);
            h0 = fmaf(t, s0[j], h0);
            h1 = fmaf(t, s1[j], h1);
        }
        hp[2 * n] = h0; hp[2 * n + 1] = h1;
        float sl = dinv[n] * dinv[n];
        agg2[2 * n] = sl * h0; agg2[2 * n + 1] = sl * h1;
    }
}

__global__ void k_edge_agg2_fb(const int* __restrict__ src, const int* __restrict__ dst,
                               const float* __restrict__ w, const float* __restrict__ dinv,
                               const float* __restrict__ hp, float* __restrict__ agg2) {
    int gid = blockIdx.x * blockDim.x + threadIdx.x;
    int T = gridDim.x * blockDim.x;
    for (int e = gid; e < NE; e += T) {
        int s = src[e], d = dst[e];
        float nrm = dinv[s] * w[e] * dinv[d];
        float2 h = *reinterpret_cast<const float2*>(hp + 2 * s);
        atomicAdd(&agg2[2 * d],     nrm * h.x);
        atomicAdd(&agg2[2 * d + 1], nrm * h.y);
    }
}

__global__ void k_pool_fb(const float* __restrict__ agg2, const int* __restrict__ batch,
                          float* __restrict__ pooled, float* __restrict__ cnt) {
    __shared__ float ls0[NG], ls1[NG], lc[NG];
    if (threadIdx.x < NG) { ls0[threadIdx.x] = 0.f; ls1[threadIdx.x] = 0.f; lc[threadIdx.x] = 0.f; }
    __syncthreads();
    int gid = blockIdx.x * blockDim.x + threadIdx.x;
    int T = gridDim.x * blockDim.x;
    for (int n = gid; n < NN; n += T) {
        int b = batch[n];
        float2 v = *reinterpret_cast<const float2*>(agg2 + 2 * n);
        atomicAdd(&ls0[b], v.x); atomicAdd(&ls1[b], v.y); atomicAdd(&lc[b], 1.f);
    }
    __syncthreads();
    if (threadIdx.x < NG) {
        int g = threadIdx.x;
        atomicAdd(&pooled[2 * g], ls0[g]);
        atomicAdd(&pooled[2 * g + 1], ls1[g]);
        atomicAdd(&cnt[g], lc[g]);
    }
}

extern "C" void kernel_launch(void* const* d_in, const int* in_sizes, int n_in,
                              void* d_out, int out_size, void* d_ws, size_t ws_size,
                              hipStream_t stream) {
    const float* x     = (const float*)d_in[0];
    const int*   ei    = (const int*)  d_in[1];
    const float* ew    = (const float*)d_in[2];
    const int*   batch = (const int*)  d_in[3];
    const float* W1    = (const float*)d_in[4];
    const float* gamma = (const float*)d_in[6];
    const float* beta  = (const float*)d_in[7];
    const float* W2    = (const float*)d_in[8];
    const float* b2    = (const float*)d_in[9];
    float* out = (float*)d_out;

    float* ws = (float*)d_ws;
    float* dinv   = ws;                 // [NN]
    float* g1     = ws + NN;            // [NN]
    float* agg1   = ws + 2 * NN;        // [NN]
    float* hp     = ws + 3 * NN;        // [2*NN] (fallback only)
    float* g2     = ws + 5 * NN;        // [2*NN]
    float* agg2   = ws + 7 * NN;        // [2*NN] (fallback only)
    float* scal   = ws + 9 * NN;        // [16]
    float* cbuf   = ws + 9 * NN + 16;   // [64] (fallback only)
    float* pooled = ws + 9 * NN + 80;   // [128]
    float* cnt    = ws + 9 * NN + 208;  // [64]  (ends 272)
    int*   cntmat   = (int*)(ws + 9 * NN + 272);            // [BB*RB] = 50176
    int*   startmat = cntmat + BB * RB;                      // [BB*RB] = 50176
    int*   bmeta    = startmat + BB * RB;                    // [256]
    uint2* ebuf     = (uint2*)(ws + 9 * NN + 272 + 100608);  // [NE] uint2

    const int* srcp = ei;
    const int* dstp = ei + NE;

    size_t availF = ws_size / sizeof(float);
    size_t needF  = 9 * (size_t)NN + 272 + 100608 + 2 * (size_t)NE + 64;

    const int NB = (NN + TPB - 1) / TPB;

    if (availF >= needF) {
        // ---- bucketed gather path, fully fused ----
        k_count  <<<BB, 1024, 0, stream>>>(dstp, cntmat, scal, pooled, cnt);
        k_scan   <<<1, 1024, 0, stream>>>(cntmat, startmat, bmeta);
        k_scatter<<<BB, 1024, 0, stream>>>(srcp, dstp, ew, startmat, bmeta, ebuf);
        kB_deg   <<<RB, 1024, 0, stream>>>(ebuf, bmeta, x, batch, dinv, g1, cnt);
        kB_t1    <<<RB, 1024, 0, stream>>>(ebuf, bmeta, g1, dinv, agg1, scal);
        k_node_hp<<<NB, TPB, 0, stream>>>(agg1, dinv, scal, W1, gamma, beta, W2, g2);
        kB_t2    <<<RB, 1024, 0, stream>>>(ebuf, bmeta, g2, dinv, batch, pooled);
        k_final  <<<1, 128, 0, stream>>>(pooled, cnt, b2, out);
    } else {
        // ---- fallback atomic path (tiny scratch) ----
        const int ebl = 2048;
        hipMemsetAsync(dinv, 0, NN * sizeof(float), stream);
        k_edge_deg_fb <<<ebl, TPB, 0, stream>>>(dstp, ew, dinv);
        k_node_dinv_fb<<<NB, TPB, 0, stream>>>(x, dinv, agg1, scal);
        k_edge_agg1_fb<<<ebl, TPB, 0, stream>>>(srcp, dstp, ew, dinv, x, agg1);
        k_reduce_fb   <<<256, TPB, 0, stream>>>(agg1, scal);
        k_prep_fb     <<<1, 64, 0, stream>>>(scal, W1, gamma, cbuf, pooled, cnt);
        k_node_hp_fb  <<<NB, TPB, 0, stream>>>(agg1, dinv, cbuf, beta, W2, scal, hp, agg2);
        k_edge_agg2_fb<<<ebl, TPB, 0, stream>>>(srcp, dstp, ew, dinv, hp, agg2);
        k_pool_fb     <<<128, TPB, 0, stream>>>(agg2, batch, pooled, cnt);
        k_final       <<<1, 128, 0, stream>>>(pooled, cnt, b2, out);
    }
}

// Round 6
// 89.114 us; speedup vs baseline: 1.6030x; 1.6030x over previous
//
#include <hip/hip_runtime.h>

#define NN 100000
#define NE 1600000
#define NH 64
#define NG 64

#define RSH 9
#define RNG 512            // bucket width (nodes per bucket)
#define RB  196            // ceil(NN/RNG)
#define BB  256            // count/scatter blocks

static constexpr int TPB = 256;

// ================= bucket build =================

// counts per (bucket, block) [transposed: cntmat[r*BB+b]]; block 0 zeros accumulators
__global__ __launch_bounds__(1024) void k_count(const int* __restrict__ dst,
                                                int* __restrict__ cntmat,
                                                float* __restrict__ scal,
                                                float* __restrict__ pooled,
                                                float* __restrict__ cnt) {
    __shared__ int cl[RB];
    for (int i = threadIdx.x; i < RB; i += 1024) cl[i] = 0;
    __syncthreads();
    int b = blockIdx.x;
    long e0 = ((long)b * NE / BB) & ~3L;
    long e1 = (b == BB - 1) ? NE : (((long)(b + 1) * NE / BB) & ~3L);
    for (long e = e0 + (long)threadIdx.x * 4; e < e1; e += 4096L) {
        int4 d4 = *reinterpret_cast<const int4*>(dst + e);
        atomicAdd(&cl[d4.x >> RSH], 1);
        atomicAdd(&cl[d4.y >> RSH], 1);
        atomicAdd(&cl[d4.z >> RSH], 1);
        atomicAdd(&cl[d4.w >> RSH], 1);
    }
    __syncthreads();
    for (int i = threadIdx.x; i < RB; i += 1024) cntmat[i * BB + b] = cl[i];
    if (b == 0) {
        if (threadIdx.x < 2)   scal[threadIdx.x] = 0.f;
        if (threadIdx.x < 128) pooled[threadIdx.x] = 0.f;
        if (threadIdx.x < NG)  cnt[threadIdx.x] = 0.f;
    }
}

// per-bucket scan over the 256 chunk counts: one block per bucket, coalesced
__global__ __launch_bounds__(BB) void k_scan_cols(const int* __restrict__ cntmat,
                                                  int* __restrict__ startmat,
                                                  int* __restrict__ colsum) {
    int r = blockIdx.x;
    int tid = threadIdx.x, lane = tid & 63, wave = tid >> 6;
    int v = cntmat[r * BB + tid];
    int incl = v;
    for (int off = 1; off < 64; off <<= 1) {
        int t = __shfl_up(incl, off);
        if (lane >= off) incl += t;
    }
    __shared__ int wsum[4];
    if (lane == 63) wsum[wave] = incl;
    __syncthreads();
    int carry = 0;
#pragma unroll
    for (int wi = 0; wi < 4; ++wi) carry += (wi < wave) ? wsum[wi] : 0;
    int excl = carry + incl - v;
    startmat[r * BB + tid] = excl;
    if (tid == BB - 1) colsum[r] = excl + v;
}

// scan of 196 bucket totals -> bucket bases
__global__ __launch_bounds__(BB) void k_scan_base(const int* __restrict__ colsum,
                                                  int* __restrict__ bmeta) {
    int tid = threadIdx.x, lane = tid & 63, wave = tid >> 6;
    int v = (tid < RB) ? colsum[tid] : 0;
    int incl = v;
    for (int off = 1; off < 64; off <<= 1) {
        int t = __shfl_up(incl, off);
        if (lane >= off) incl += t;
    }
    __shared__ int wsum[4];
    if (lane == 63) wsum[wave] = incl;
    __syncthreads();
    int carry = 0;
#pragma unroll
    for (int wi = 0; wi < 4; ++wi) carry += (wi < wave) ? wsum[wi] : 0;
    int excl = carry + incl - v;
    if (tid < RB) bmeta[tid] = excl;
    if (tid == RB - 1) bmeta[RB] = excl + v;
}

// scatter edges into buckets: ebuf[slot] = { (dstoff<<17)|src , w }
__global__ __launch_bounds__(1024) void k_scatter(const int* __restrict__ src,
                                                  const int* __restrict__ dst,
                                                  const float* __restrict__ w,
                                                  const int* __restrict__ startmat,
                                                  const int* __restrict__ bmeta,
                                                  uint2* __restrict__ ebuf) {
    __shared__ int curs[RB];
    int b = blockIdx.x;
    for (int i = threadIdx.x; i < RB; i += 1024) curs[i] = startmat[i * BB + b] + bmeta[i];
    __syncthreads();
    long e0 = ((long)b * NE / BB) & ~3L;
    long e1 = (b == BB - 1) ? NE : (((long)(b + 1) * NE / BB) & ~3L);
    for (long e = e0 + (long)threadIdx.x * 4; e < e1; e += 4096L) {
        int4 d4 = *reinterpret_cast<const int4*>(dst + e);
        int4 s4 = *reinterpret_cast<const int4*>(src + e);
        float4 w4 = *reinterpret_cast<const float4*>(w + e);
        int dd[4] = {d4.x, d4.y, d4.z, d4.w};
        int ss[4] = {s4.x, s4.y, s4.z, s4.w};
        float wv[4] = {w4.x, w4.y, w4.z, w4.w};
#pragma unroll
        for (int k = 0; k < 4; ++k) {
            int r = dd[k] >> RSH;
            int slot = atomicAdd(&curs[r], 1);
            unsigned pack = ((unsigned)(dd[k] & (RNG - 1)) << 17) | (unsigned)ss[k];
            ebuf[slot] = make_uint2(pack, __float_as_uint(wv[k]));
        }
    }
}

// ================= fused gather passes (one block per bucket) =================

// deg: bins += w; then dinv/g1 finalized for this block's node range + graph counts
__global__ __launch_bounds__(1024) void kB_deg(const uint2* __restrict__ ebuf,
                                               const int* __restrict__ bmeta,
                                               const float* __restrict__ x,
                                               const int* __restrict__ batch,
                                               float* __restrict__ dinv,
                                               float* __restrict__ g1,
                                               float* __restrict__ cnt) {
    __shared__ float bins[RNG];
    __shared__ int hist[NG];
    int r = blockIdx.x;
    if (threadIdx.x < RNG) bins[threadIdx.x] = 0.f;
    if (threadIdx.x >= RNG && threadIdx.x < RNG + NG) hist[threadIdx.x - RNG] = 0;
    __syncthreads();
    int s = bmeta[r], e = bmeta[r + 1];
    for (int i = s + threadIdx.x; i < e; i += 1024) {
        uint2 ed = ebuf[i];
        atomicAdd(&bins[ed.x >> 17], __uint_as_float(ed.y));
    }
    __syncthreads();
    int base = r * RNG;
    int len = min(RNG, NN - base);
    if (threadIdx.x < len) {
        int n = base + threadIdx.x;
        float di = rsqrtf(bins[threadIdx.x] + 1.0f);
        dinv[n] = di;
        g1[n] = di * x[n];
        atomicAdd(&hist[batch[n]], 1);
    }
    __syncthreads();
    if (threadIdx.x < NG && hist[threadIdx.x] > 0)
        atomicAdd(&cnt[threadIdx.x], (float)hist[threadIdx.x]);
}

// t1: bins += w*g1[src]; agg1 finalized for this range; BN sum/sumsq atomics
__global__ __launch_bounds__(1024) void kB_t1(const uint2* __restrict__ ebuf,
                                              const int* __restrict__ bmeta,
                                              const float* __restrict__ g1,
                                              const float* __restrict__ dinv,
                                              float* __restrict__ agg1,
                                              float* __restrict__ scal) {
    __shared__ float bins[RNG];
    int r = blockIdx.x;
    if (threadIdx.x < RNG) bins[threadIdx.x] = 0.f;
    __syncthreads();
    int s = bmeta[r], e = bmeta[r + 1];
    for (int i = s + threadIdx.x; i < e; i += 1024) {
        uint2 ed = ebuf[i];
        atomicAdd(&bins[ed.x >> 17], __uint_as_float(ed.y) * g1[ed.x & 0x1FFFF]);
    }
    __syncthreads();
    int base = r * RNG;
    int len = min(RNG, NN - base);
    float a = 0.f;
    if (threadIdx.x < len) {
        int n = base + threadIdx.x;
        a = dinv[n] * (bins[threadIdx.x] + g1[n]);
        agg1[n] = a;
    }
    float sm = a, q = a * a;
    for (int off = 32; off > 0; off >>= 1) {
        sm += __shfl_down(sm, off);
        q  += __shfl_down(q, off);
    }
    __shared__ float red[2][16];
    int wave = threadIdx.x >> 6, lane = threadIdx.x & 63;
    if (lane == 0) { red[0][wave] = sm; red[1][wave] = q; }
    __syncthreads();
    if (threadIdx.x == 0) {
        float ss = 0.f, qq = 0.f;
        for (int i = 0; i < 16; ++i) { ss += red[0][i]; qq += red[1][i]; }
        atomicAdd(&scal[0], ss);
        atomicAdd(&scal[1], qq);
    }
}

// node pass (prep inlined): g2[n][k] = dinv * sum_j relu((agg1-mu)*c[j]+beta[j]) * W2[j][k]
__global__ void k_node_hp(const float* __restrict__ agg1, const float* __restrict__ dinv,
                          const float* __restrict__ scal, const float* __restrict__ W1,
                          const float* __restrict__ gamma, const float* __restrict__ beta,
                          const float* __restrict__ W2, float* __restrict__ g2) {
    __shared__ float sc[NH], sb[NH], s0[NH], s1[NH];
    float mu  = scal[0] * (1.0f / NN);
    if (threadIdx.x < NH) {
        int j = threadIdx.x;
        float var = scal[1] * (1.0f / NN) - mu * mu;
        float w1 = W1[j];
        sc[j] = w1 * gamma[j] * rsqrtf(var * w1 * w1 + 1e-5f);
        sb[j] = beta[j]; s0[j] = W2[2 * j]; s1[j] = W2[2 * j + 1];
    }
    __syncthreads();
    int n = blockIdx.x * blockDim.x + threadIdx.x;
    if (n < NN) {
        float a = agg1[n] - mu;
        float h0 = 0.f, h1 = 0.f;
#pragma unroll
        for (int j = 0; j < NH; ++j) {
            float t = fmaxf(fmaf(a, sc[j], sb[j]), 0.f);
            h0 = fmaf(t, s0[j], h0);
            h1 = fmaf(t, s1[j], h1);
        }
        float di = dinv[n];
        g2[2 * n] = di * h0; g2[2 * n + 1] = di * h1;
    }
}

// t2: bins += w*g2[src]; agg2 finalized in-register; pooled via LDS graph bins
__global__ __launch_bounds__(1024) void kB_t2(const uint2* __restrict__ ebuf,
                                              const int* __restrict__ bmeta,
                                              const float* __restrict__ g2,
                                              const float* __restrict__ dinv,
                                              const int* __restrict__ batch,
                                              float* __restrict__ pooled) {
    __shared__ float2 bins[RNG];
    __shared__ float pl[NG][2];
    int r = blockIdx.x;
    if (threadIdx.x < RNG) bins[threadIdx.x] = make_float2(0.f, 0.f);
    if (threadIdx.x >= RNG && threadIdx.x < RNG + 2 * NG)
        ((float*)pl)[threadIdx.x - RNG] = 0.f;
    __syncthreads();
    int s = bmeta[r], e = bmeta[r + 1];
    for (int i = s + threadIdx.x; i < e; i += 1024) {
        uint2 ed = ebuf[i];
        int sidx = ed.x & 0x1FFFF;
        float ww = __uint_as_float(ed.y);
        float2 g = *reinterpret_cast<const float2*>(g2 + 2 * sidx);
        int off = ed.x >> 17;
        atomicAdd(&bins[off].x, ww * g.x);
        atomicAdd(&bins[off].y, ww * g.y);
    }
    __syncthreads();
    int base = r * RNG;
    int len = min(RNG, NN - base);
    if (threadIdx.x < len) {
        int n = base + threadIdx.x;
        float di = dinv[n];
        float a0 = di * (bins[threadIdx.x].x + g2[2 * n]);
        float a1 = di * (bins[threadIdx.x].y + g2[2 * n + 1]);
        int g = batch[n];
        atomicAdd(&pl[g][0], a0);
        atomicAdd(&pl[g][1], a1);
    }
    __syncthreads();
    if (threadIdx.x < NG) {
        float p0 = pl[threadIdx.x][0], p1 = pl[threadIdx.x][1];
        if (p0 != 0.f || p1 != 0.f) {
            atomicAdd(&pooled[2 * threadIdx.x],     p0);
            atomicAdd(&pooled[2 * threadIdx.x + 1], p1);
        }
    }
}

__global__ void k_final(const float* __restrict__ pooled, const float* __restrict__ cnt,
                        const float* __restrict__ b2, float* __restrict__ out) {
    int i = threadIdx.x;
    if (i < 2 * NG) {
        int g = i >> 1, k = i & 1;
        float cg = cnt[g];
        out[i] = pooled[i] / fmaxf(cg, 1.0f) + (cg > 0.f ? b2[k] : 0.f);
    }
}

// ================= fallback (atomic) path, used only if scratch is tiny =================

__global__ void k_edge_deg_fb(const int* __restrict__ dst, const float* __restrict__ w,
                              float* __restrict__ deg) {
    int gid = blockIdx.x * blockDim.x + threadIdx.x;
    int T = gridDim.x * blockDim.x;
    for (int e = gid; e < NE; e += T) atomicAdd(&deg[dst[e]], w[e]);
}

__global__ void k_node_dinv_fb(const float* __restrict__ x, float* __restrict__ deg,
                               float* __restrict__ agg1, float* __restrict__ scal) {
    int gid = blockIdx.x * blockDim.x + threadIdx.x;
    int T = gridDim.x * blockDim.x;
    for (int n = gid; n < NN; n += T) {
        float di = rsqrtf(deg[n] + 1.0f);
        deg[n] = di;
        agg1[n] = di * di * x[n];
    }
    if (gid == 0) { scal[0] = 0.f; scal[1] = 0.f; }
}

__global__ void k_edge_agg1_fb(const int* __restrict__ src, const int* __restrict__ dst,
                               const float* __restrict__ w, const float* __restrict__ dinv,
                               const float* __restrict__ x, float* __restrict__ agg1) {
    int gid = blockIdx.x * blockDim.x + threadIdx.x;
    int T = gridDim.x * blockDim.x;
    for (int e = gid; e < NE; e += T) {
        int s = src[e], d = dst[e];
        atomicAdd(&agg1[d], dinv[s] * w[e] * dinv[d] * x[s]);
    }
}

__global__ void k_reduce_fb(const float* __restrict__ agg1, float* __restrict__ scal) {
    float s = 0.f, q = 0.f;
    int gid = blockIdx.x * blockDim.x + threadIdx.x;
    int T = gridDim.x * blockDim.x;
    for (int n = gid; n < NN; n += T) { float a = agg1[n]; s += a; q += a * a; }
    for (int off = 32; off > 0; off >>= 1) { s += __shfl_down(s, off); q += __shfl_down(q, off); }
    __shared__ float red[2][4];
    int wave = threadIdx.x >> 6, lane = threadIdx.x & 63;
    if (lane == 0) { red[0][wave] = s; red[1][wave] = q; }
    __syncthreads();
    if (threadIdx.x == 0) {
        atomicAdd(&scal[0], red[0][0] + red[0][1] + red[0][2] + red[0][3]);
        atomicAdd(&scal[1], red[1][0] + red[1][1] + red[1][2] + red[1][3]);
    }
}

__global__ void k_prep_fb(float* __restrict__ scal, const float* __restrict__ W1,
                          const float* __restrict__ gamma, float* __restrict__ c,
                          float* __restrict__ pooled, float* __restrict__ cnt) {
    int j = threadIdx.x;
    float mu  = scal[0] * (1.0f / NN);
    float var = scal[1] * (1.0f / NN) - mu * mu;
    float w1 = W1[j];
    c[j] = w1 * gamma[j] * rsqrtf(var * w1 * w1 + 1e-5f);
    pooled[2 * j] = 0.f; pooled[2 * j + 1] = 0.f; cnt[j] = 0.f;
    if (j == 0) scal[2] = mu;
}

__global__ void k_node_hp_fb(const float* __restrict__ agg1, const float* __restrict__ dinv,
                             const float* __restrict__ c, const float* __restrict__ beta,
                             const float* __restrict__ W2, const float* __restrict__ scal,
                             float* __restrict__ hp, float* __restrict__ agg2) {
    __shared__ float sc[NH], sb[NH], s0[NH], s1[NH];
    if (threadIdx.x < NH) {
        int j = threadIdx.x;
        sc[j] = c[j]; sb[j] = beta[j]; s0[j] = W2[2 * j]; s1[j] = W2[2 * j + 1];
    }
    __syncthreads();
    float mu = scal[2];
    int n = blockIdx.x * blockDim.x + threadIdx.x;
    if (n < NN) {
        float a = agg1[n] - mu;
        float h0 = 0.f, h1 = 0.f;
#pragma unroll
        for (int j = 0; j < NH; ++j) {
            float t = fmaxf(fmaf(a, sc[j], sb[j]), 0.f);
            h0 = fmaf(t, s0[j], h0);
            h1 = fmaf(t, s1[j], h1);
        }
        hp[2 * n] = h0; hp[2 * n + 1] = h1;
        float sl = dinv[n] * dinv[n];
        agg2[2 * n] = sl * h0; agg2[2 * n + 1] = sl * h1;
    }
}

__global__ void k_edge_agg2_fb(const int* __restrict__ src, const int* __restrict__ dst,
                               const float* __restrict__ w, const float* __restrict__ dinv,
                               const float* __restrict__ hp, float* __restrict__ agg2) {
    int gid = blockIdx.x * blockDim.x + threadIdx.x;
    int T = gridDim.x * blockDim.x;
    for (int e = gid; e < NE; e += T) {
        int s = src[e], d = dst[e];
        float nrm = dinv[s] * w[e] * dinv[d];
        float2 h = *reinterpret_cast<const float2*>(hp + 2 * s);
        atomicAdd(&agg2[2 * d],     nrm * h.x);
        atomicAdd(&agg2[2 * d + 1], nrm * h.y);
    }
}

__global__ void k_pool_fb(const float* __restrict__ agg2, const int* __restrict__ batch,
                          float* __restrict__ pooled, float* __restrict__ cnt) {
    __shared__ float ls0[NG], ls1[NG], lc[NG];
    if (threadIdx.x < NG) { ls0[threadIdx.x] = 0.f; ls1[threadIdx.x] = 0.f; lc[threadIdx.x] = 0.f; }
    __syncthreads();
    int gid = blockIdx.x * blockDim.x + threadIdx.x;
    int T = gridDim.x * blockDim.x;
    for (int n = gid; n < NN; n += T) {
        int b = batch[n];
        float2 v = *reinterpret_cast<const float2*>(agg2 + 2 * n);
        atomicAdd(&ls0[b], v.x); atomicAdd(&ls1[b], v.y); atomicAdd(&lc[b], 1.f);
    }
    __syncthreads();
    if (threadIdx.x < NG) {
        int g = threadIdx.x;
        atomicAdd(&pooled[2 * g], ls0[g]);
        atomicAdd(&pooled[2 * g + 1], ls1[g]);
        atomicAdd(&cnt[g], lc[g]);
    }
}

extern "C" void kernel_launch(void* const* d_in, const int* in_sizes, int n_in,
                              void* d_out, int out_size, void* d_ws, size_t ws_size,
                              hipStream_t stream) {
    const float* x     = (const float*)d_in[0];
    const int*   ei    = (const int*)  d_in[1];
    const float* ew    = (const float*)d_in[2];
    const int*   batch = (const int*)  d_in[3];
    const float* W1    = (const float*)d_in[4];
    const float* gamma = (const float*)d_in[6];
    const float* beta  = (const float*)d_in[7];
    const float* W2    = (const float*)d_in[8];
    const float* b2    = (const float*)d_in[9];
    float* out = (float*)d_out;

    float* ws = (float*)d_ws;
    float* dinv   = ws;                 // [NN]
    float* g1     = ws + NN;            // [NN]
    float* agg1   = ws + 2 * NN;        // [NN]
    float* hp     = ws + 3 * NN;        // [2*NN] (fallback only)
    float* g2     = ws + 5 * NN;        // [2*NN]
    float* agg2   = ws + 7 * NN;        // [2*NN] (fallback only)
    float* scal   = ws + 9 * NN;        // [16]
    float* cbuf   = ws + 9 * NN + 16;   // [64] (fallback only)
    float* pooled = ws + 9 * NN + 80;   // [128]
    float* cnt    = ws + 9 * NN + 208;  // [64]  (ends 272)
    int*   cntmat   = (int*)(ws + 9 * NN + 272);   // [RB*BB] = 50176
    int*   startmat = cntmat + RB * BB;            // [RB*BB] = 50176
    int*   bmeta    = startmat + RB * BB;          // [256]
    int*   colsum   = bmeta + 256;                 // [256]   (ints end at 100864)
    uint2* ebuf     = (uint2*)(ws + 9 * NN + 272 + 100864);  // [NE] uint2

    const int* srcp = ei;
    const int* dstp = ei + NE;

    size_t availF = ws_size / sizeof(float);
    size_t needF  = 9 * (size_t)NN + 272 + 100864 + 2 * (size_t)NE + 64;

    const int NB = (NN + TPB - 1) / TPB;

    if (availF >= needF) {
        // ---- bucketed gather path, fully fused, parallel scan ----
        k_count    <<<BB, 1024, 0, stream>>>(dstp, cntmat, scal, pooled, cnt);
        k_scan_cols<<<RB, BB, 0, stream>>>(cntmat, startmat, colsum);
        k_scan_base<<<1, BB, 0, stream>>>(colsum, bmeta);
        k_scatter  <<<BB, 1024, 0, stream>>>(srcp, dstp, ew, startmat, bmeta, ebuf);
        kB_deg     <<<RB, 1024, 0, stream>>>(ebuf, bmeta, x, batch, dinv, g1, cnt);
        kB_t1      <<<RB, 1024, 0, stream>>>(ebuf, bmeta, g1, dinv, agg1, scal);
        k_node_hp  <<<NB, TPB, 0, stream>>>(agg1, dinv, scal, W1, gamma, beta, W2, g2);
        kB_t2      <<<RB, 1024, 0, stream>>>(ebuf, bmeta, g2, dinv, batch, pooled);
        k_final    <<<1, 128, 0, stream>>>(pooled, cnt, b2, out);
    } else {
        // ---- fallback atomic path (tiny scratch) ----
        const int ebl = 2048;
        hipMemsetAsync(dinv, 0, NN * sizeof(float), stream);
        k_edge_deg_fb <<<ebl, TPB, 0, stream>>>(dstp, ew, dinv);
        k_node_dinv_fb<<<NB, TPB, 0, stream>>>(x, dinv, agg1, scal);
        k_edge_agg1_fb<<<ebl, TPB, 0, stream>>>(srcp, dstp, ew, dinv, x, agg1);
        k_reduce_fb   <<<256, TPB, 0, stream>>>(agg1, scal);
        k_prep_fb     <<<1, 64, 0, stream>>>(scal, W1, gamma, cbuf, pooled, cnt);
        k_node_hp_fb  <<<NB, TPB, 0, stream>>>(agg1, dinv, cbuf, beta, W2, scal, hp, agg2);
        k_edge_agg2_fb<<<ebl, TPB, 0, stream>>>(srcp, dstp, ew, dinv, hp, agg2);
        k_pool_fb     <<<128, TPB, 0, stream>>>(agg2, batch, pooled, cnt);
        k_final       <<<1, 128, 0, stream>>>(pooled, cnt, b2, out);
    }
}